// Round 13
// baseline (118.315 us; speedup 1.0000x reference)
//
#include <hip/hip_runtime.h>
#include <hip/hip_bf16.h>
#include <math.h>

#define B_DIM 8
#define T_DIM 1024
#define D_DIM 512
#define BT (B_DIM * T_DIM)   // 8192
#define NBLK 1024            // 512 (b,t0) pairs x 2 halves

typedef __bf16 bf16x8 __attribute__((ext_vector_type(8)));
typedef float floatx4 __attribute__((ext_vector_type(4)));

__device__ __forceinline__ float wave_reduce_sum(float v) {
#pragma unroll
    for (int off = 32; off > 0; off >>= 1) v += __shfl_xor(v, off, 64);
    return v;
}

// fast stable softplus (validated R10): max(y,0)+log(1+exp(-|y|))
__device__ __forceinline__ float softplus(float y) {
    return fmaxf(y, 0.0f) + __logf(1.0f + __expf(-fabsf(y)));
}

// 8 fp32 -> bf16x8 fragment, RNE (validated rounds 7-12)
__device__ __forceinline__ bf16x8 cvt8(float4 x, float4 y) {
    union { ushort u[8]; bf16x8 v; } r;
    __hip_bfloat162 h0 = __float22bfloat162_rn(make_float2(x.x, x.y));
    __hip_bfloat162 h1 = __float22bfloat162_rn(make_float2(x.z, x.w));
    __hip_bfloat162 h2 = __float22bfloat162_rn(make_float2(y.x, y.y));
    __hip_bfloat162 h3 = __float22bfloat162_rn(make_float2(y.z, y.w));
    ushort2 p0 = *(ushort2*)&h0, p1 = *(ushort2*)&h1;
    ushort2 p2 = *(ushort2*)&h2, p3 = *(ushort2*)&h3;
    r.u[0] = p0.x; r.u[1] = p0.y; r.u[2] = p1.x; r.u[3] = p1.y;
    r.u[4] = p2.x; r.u[5] = p2.y; r.u[6] = p3.x; r.u[7] = p3.y;
    return r.v;
}

// Block = (pair, half): pair -> (b, t0). half 0: m2a tiles (m center x a 0-2);
// half 1: a2m tiles (m 0-2 x a center). 8 waves, 8-way k-split (64 elems).
// Norms in-block (R7/R9 pattern); epilogue masks = validated R7/R9.
__global__ __launch_bounds__(512, 6) void halfband_kernel(
    const float* __restrict__ m, const float* __restrict__ a,
    const float* __restrict__ pscale, const float* __restrict__ pbias,
    float* __restrict__ part_loss, float* __restrict__ part_corr)
{
    __shared__ float red[8][3][272];   // k-split score partials (stride 17)
    __shared__ float SbufA[16][49];    // half 0: S[i][v]
    __shared__ float SbufB[48][17];    // half 1: S[u][i]
    __shared__ float red2[8][4][16];   // per-wave row sumsq partials
    __shared__ float norms[4][16];     // inv-norms (slot meaning per half)
    __shared__ float qpos[16], shl[8];

    int blk  = blockIdx.x;
    int half = blk & 1;
    int pair = blk >> 1;
    int b    = pair >> 6;
    int t0   = (pair & 63) << 4;
    int tid  = threadIdx.x;
    int w    = tid >> 6;               // wave id: k-split (64 elems each)
    int lane = tid & 63;
    int mrow = lane & 15;
    int kgrp = lane >> 4;
    int koff = w * 64 + kgrp * 8;

    const float* mb = m + ((size_t)b << 19);   // b*1024*512
    const float* ab = a + ((size_t)b << 19);

    // center row (always valid) and 3 band rows (clamped; masked in epilogue)
    const float* ctr;                  // half0: m row t0+mrow; half1: a row
    const float* bnd[3];               // half0: a rows; half1: m rows
    {
        const float* cbase = half ? ab : mb;
        const float* bbase = half ? mb : ab;
        ctr = cbase + (size_t)(t0 + mrow) * D_DIM + koff;
#pragma unroll
        for (int s = 0; s < 3; ++s) {
            int r = t0 - 16 + s * 16 + mrow;
            r = min(max(r, 0), T_DIM - 1);
            bnd[s] = bbase + (size_t)r * D_DIM + koff;
        }
    }

    floatx4 acc[3] = {{0,0,0,0},{0,0,0,0},{0,0,0,0}};
    float ssc = 0.f, ssb[3] = {0.f,0.f,0.f};

#pragma unroll
    for (int ks = 0; ks < 2; ++ks) {           // 2 k-chunks of 32 per wave
        float4 x = *(const float4*)(ctr + ks * 32);
        float4 y = *(const float4*)(ctr + ks * 32 + 4);
        ssc += x.x*x.x + x.y*x.y + x.z*x.z + x.w*x.w
             + y.x*y.x + y.y*y.y + y.z*y.z + y.w*y.w;
        bf16x8 cf = cvt8(x, y);
#pragma unroll
        for (int s = 0; s < 3; ++s) {
            float4 u = *(const float4*)(bnd[s] + ks * 32);
            float4 v = *(const float4*)(bnd[s] + ks * 32 + 4);
            ssb[s] += u.x*u.x + u.y*u.y + u.z*u.z + u.w*u.w
                    + v.x*v.x + v.y*v.y + v.z*v.z + v.w*v.w;
            bf16x8 bf = cvt8(u, v);
            // half0: S[m_ctr][a_s] = mfma(A=ctr, B=band)
            // half1: S[m_s][a_ctr] = mfma(A=band, B=ctr)
            acc[s] = half
                ? __builtin_amdgcn_mfma_f32_16x16x32_bf16(bf, cf, acc[s], 0, 0, 0)
                : __builtin_amdgcn_mfma_f32_16x16x32_bf16(cf, bf, acc[s], 0, 0, 0);
        }
    }

    // sumsq: reduce across the 4 kgrp lanes of each row (xor 16, 32)
#pragma unroll
    for (int off = 16; off <= 32; off <<= 1) {
        ssc += __shfl_xor(ssc, off, 64);
#pragma unroll
        for (int s = 0; s < 3; ++s) ssb[s] += __shfl_xor(ssb[s], off, 64);
    }
    if (kgrp == 0) {
        // slots 0-2: band rows; slot 3: center rows
#pragma unroll
        for (int s = 0; s < 3; ++s) red2[w][s][mrow] = ssb[s];
        red2[w][3][mrow] = ssc;
    }
    // k-split score partials. C layout: col=lane&15, row=(lane>>4)*4+reg
#pragma unroll
    for (int s = 0; s < 3; ++s)
#pragma unroll
        for (int r = 0; r < 4; ++r)
            red[w][s][(kgrp * 4 + r) * 17 + mrow] = acc[s][r];
    __syncthreads();

    if (tid < 64) {
        int slot = tid >> 4, mr = tid & 15;
        float ss = 0.f;
#pragma unroll
        for (int ww = 0; ww < 8; ++ww) ss += red2[ww][slot][mr];
        norms[slot][mr] = 1.0f / fmaxf(sqrtf(ss), 1e-12f);
    }
    // combine 8 k-partials -> Sbuf (3 tiles x 256 entries = 768)
    {
        int e = tid;                   // 512 threads: entries tid, tid+512
#pragma unroll
        for (int rep = 0; rep < 2; ++rep, e += 512) {
            if (e < 768) {
                int q = e >> 8, r2 = e & 255;
                int rho = r2 >> 4, kap = r2 & 15;   // C row, C col
                float s4 = 0.f;
#pragma unroll
                for (int ww = 0; ww < 8; ++ww)
                    s4 += red[ww][q][rho * 17 + kap];
                if (half == 0) SbufA[rho][q * 16 + kap] = s4;  // S[i][v]
                else           SbufB[q * 16 + rho][kap] = s4;  // S[u][i]
            }
        }
    }
    __syncthreads();

    // ---- epilogue: 256 threads, masks identical to validated R7/R9 ----
    float scale = expf(pscale[0]), bias = pbias[0];
    float loss = 0.0f;

    if (tid < 256) {
        int i = tid >> 4, cc = tid & 15;
        float inv_q = norms[3][i];     // center-row inv-norm for query t0+i
        float qmax = -1e30f, qp = 0.0f;
#pragma unroll
        for (int tj = 0; tj < 3; ++tj) {
            int k  = tj * 16 + cc;
            int dd = k - i;                    // (other - t) + 16
            int o  = t0 - 16 + k;              // other index
            if (dd >= 0 && dd < 32 && o >= 0 && o < T_DIM) {
                float sv = (half == 0 ? SbufA[i][k] : SbufB[k][i])
                         * norms[tj][cc];      // * inv-norm of other row
                float logit = sv * inv_q * scale + bias;
                bool pos = (dd >= 12) && (dd <= 19);
                loss += softplus(pos ? -logit : logit);
                if (sv > qmax) { qmax = sv; qp = pos ? 1.0f : 0.0f; }
            }
        }
#pragma unroll
        for (int off = 1; off < 16; off <<= 1) {
            float ov = __shfl_xor(qmax, off, 64);
            float op = __shfl_xor(qp, off, 64);
            if (ov > qmax) { qmax = ov; qp = op; }
        }
        if (cc == 0) qpos[i] = qp;
    }

    loss = wave_reduce_sum(loss);
    if (lane == 0) shl[w] = loss;
    __syncthreads();
    if (tid == 0) {
        float L = 0.0f, C = 0.0f;
#pragma unroll
        for (int r = 0; r < 8; ++r) L += shl[r];
#pragma unroll
        for (int r = 0; r < 16; ++r) C += qpos[r];
        part_loss[blk] = L;
        part_corr[blk] = C;
    }
}

__global__ __launch_bounds__(256) void finalsum_kernel(
    const float* __restrict__ part_loss, const float* __restrict__ part_corr,
    float* __restrict__ out)
{
    int tid = threadIdx.x;
    float l = 0.f, c = 0.f;
#pragma unroll
    for (int j = 0; j < 4; ++j) {
        l += part_loss[tid + j * 256];
        c += part_corr[tid + j * 256];
    }
    l = wave_reduce_sum(l);
    c = wave_reduce_sum(c);
    __shared__ float shl[4], shc[4];
    int w = tid >> 6, lane = tid & 63;
    if (lane == 0) { shl[w] = l; shc[w] = c; }
    __syncthreads();
    if (tid == 0) {
        out[0] = (shl[0] + shl[1] + shl[2] + shl[3]) / 16384.0f;
        out[1] = (shc[0] + shc[1] + shc[2] + shc[3]) / 16384.0f;
    }
}

extern "C" void kernel_launch(void* const* d_in, const int* in_sizes, int n_in,
                              void* d_out, int out_size, void* d_ws, size_t ws_size,
                              hipStream_t stream)
{
    const float* m  = (const float*)d_in[0];
    const float* a  = (const float*)d_in[1];
    const float* ps = (const float*)d_in[2];
    const float* pb = (const float*)d_in[3];
    float* out = (float*)d_out;

    float* part_loss = (float*)d_ws;          // 1024
    float* part_corr = part_loss + NBLK;      // 1024

    halfband_kernel<<<NBLK, 512, 0, stream>>>(m, a, ps, pb,
                                              part_loss, part_corr);
    finalsum_kernel<<<1, 256, 0, stream>>>(part_loss, part_corr, out);
}

// Round 14
// 90.434 us; speedup vs baseline: 1.3083x; 1.3083x over previous
//
#include <hip/hip_runtime.h>
#include <hip/hip_bf16.h>
#include <math.h>

#define B_DIM 8
#define T_DIM 1024
#define D_DIM 512
#define BT (B_DIM * T_DIM)   // 8192
#define NBLK 512             // 8 batches x 64 tiles of 16 queries

typedef __bf16 bf16x8 __attribute__((ext_vector_type(8)));
typedef float floatx4 __attribute__((ext_vector_type(4)));

__device__ __forceinline__ float wave_reduce_sum(float v) {
#pragma unroll
    for (int off = 32; off > 0; off >>= 1) v += __shfl_xor(v, off, 64);
    return v;
}

// fast stable softplus (validated R10/R12): max(y,0)+log(1+exp(-|y|))
__device__ __forceinline__ float softplus(float y) {
    return fmaxf(y, 0.0f) + __logf(1.0f + __expf(-fabsf(y)));
}

// 8 fp32 -> bf16x8 fragment, RNE (validated rounds 7-13)
__device__ __forceinline__ bf16x8 cvt8(float4 x, float4 y) {
    union { ushort u[8]; bf16x8 v; } r;
    __hip_bfloat162 h0 = __float22bfloat162_rn(make_float2(x.x, x.y));
    __hip_bfloat162 h1 = __float22bfloat162_rn(make_float2(x.z, x.w));
    __hip_bfloat162 h2 = __float22bfloat162_rn(make_float2(y.x, y.y));
    __hip_bfloat162 h3 = __float22bfloat162_rn(make_float2(y.z, y.w));
    ushort2 p0 = *(ushort2*)&h0, p1 = *(ushort2*)&h1;
    ushort2 p2 = *(ushort2*)&h2, p3 = *(ushort2*)&h3;
    r.u[0] = p0.x; r.u[1] = p0.y; r.u[2] = p1.x; r.u[3] = p1.y;
    r.u[4] = p2.x; r.u[5] = p2.y; r.u[6] = p3.x; r.u[7] = p3.y;
    return r.v;
}

// R9-validated crossband (90.7 us champion), with XCD swizzle: b = blk & 7 so
// (if blockIdx%8 -> XCD) each XCD's L2 holds its batch's 4 MB working set and
// the 3x halo re-reads become L2 hits. Speed-only heuristic (G16-safe).
__global__ __launch_bounds__(512, 4) void crossband_kernel(
    const float* __restrict__ m, const float* __restrict__ a,
    const float* __restrict__ pscale, const float* __restrict__ pbias,
    float* __restrict__ part_loss, float* __restrict__ part_corr)
{
    __shared__ float red[8][5][272];   // k-split score partials (stride 17)
    __shared__ float Sbuf[48][49];     // summed raw scores (cross region used)
    __shared__ float red2[8][6][16];   // per-wave row sumsq partials
    __shared__ float norms[6][16];     // inv-norms: slots 0-2 m, 3-5 a
    __shared__ float rowpos[16], colpos[16], shl[8];

    int blk = blockIdx.x;
    int b   = blk & 7;                 // XCD-local batch
    int t0  = (blk >> 3) << 4;
    int tid  = threadIdx.x;
    int w    = tid >> 6;               // wave id: k-split (64 elems each)
    int lane = tid & 63;
    int mrow = lane & 15;
    int kgrp = lane >> 4;
    int koff = w * 64 + kgrp * 8;

    const float* mb = m + ((size_t)b << 19);   // b*1024*512
    const float* ab = a + ((size_t)b << 19);

    const float* mp[3]; const float* ap[3];
#pragma unroll
    for (int s = 0; s < 3; ++s) {
        int r = t0 - 16 + s * 16 + mrow;       // clamped; masked in epilogue
        r = min(max(r, 0), T_DIM - 1);
        mp[s] = mb + (size_t)r * D_DIM + koff;
        ap[s] = ab + (size_t)r * D_DIM + koff;
    }

    // 5 cross tiles: q -> (ti, tj): 0:(1,0) 1:(1,1) 2:(1,2) 3:(0,1) 4:(2,1)
    floatx4 acc[5];
#pragma unroll
    for (int q = 0; q < 5; ++q) acc[q] = (floatx4){0.f,0.f,0.f,0.f};
    float ssm[3] = {0.f,0.f,0.f}, ssa[3] = {0.f,0.f,0.f};

#pragma unroll
    for (int ks = 0; ks < 2; ++ks) {           // 2 k-chunks of 32 per wave
        bf16x8 am[3], av[3];
#pragma unroll
        for (int s = 0; s < 3; ++s) {
            float4 x = *(const float4*)(mp[s] + ks * 32);
            float4 y = *(const float4*)(mp[s] + ks * 32 + 4);
            ssm[s] += x.x*x.x + x.y*x.y + x.z*x.z + x.w*x.w
                    + y.x*y.x + y.y*y.y + y.z*y.z + y.w*y.w;
            am[s] = cvt8(x, y);
            float4 u = *(const float4*)(ap[s] + ks * 32);
            float4 v = *(const float4*)(ap[s] + ks * 32 + 4);
            ssa[s] += u.x*u.x + u.y*u.y + u.z*u.z + u.w*u.w
                    + v.x*v.x + v.y*v.y + v.z*v.z + v.w*v.w;
            av[s] = cvt8(u, v);
        }
        acc[0] = __builtin_amdgcn_mfma_f32_16x16x32_bf16(am[1], av[0], acc[0], 0, 0, 0);
        acc[1] = __builtin_amdgcn_mfma_f32_16x16x32_bf16(am[1], av[1], acc[1], 0, 0, 0);
        acc[2] = __builtin_amdgcn_mfma_f32_16x16x32_bf16(am[1], av[2], acc[2], 0, 0, 0);
        acc[3] = __builtin_amdgcn_mfma_f32_16x16x32_bf16(am[0], av[1], acc[3], 0, 0, 0);
        acc[4] = __builtin_amdgcn_mfma_f32_16x16x32_bf16(am[2], av[1], acc[4], 0, 0, 0);
    }

    // sumsq: reduce across the 4 kgrp lanes of each row (xor 16, 32)
#pragma unroll
    for (int off = 16; off <= 32; off <<= 1) {
#pragma unroll
        for (int s = 0; s < 3; ++s) {
            ssm[s] += __shfl_xor(ssm[s], off, 64);
            ssa[s] += __shfl_xor(ssa[s], off, 64);
        }
    }
    if (kgrp == 0) {
#pragma unroll
        for (int s = 0; s < 3; ++s) {
            red2[w][s][mrow]     = ssm[s];
            red2[w][3 + s][mrow] = ssa[s];
        }
    }
    // k-split score partials. C layout: col=lane&15, row=(lane>>4)*4+reg
#pragma unroll
    for (int q = 0; q < 5; ++q)
#pragma unroll
        for (int r = 0; r < 4; ++r)
            red[w][q][(kgrp * 4 + r) * 17 + mrow] = acc[q][r];
    __syncthreads();

    if (tid < 96) {
        int slot = tid >> 4, mr = tid & 15;
        float ss = 0.f;
#pragma unroll
        for (int ww = 0; ww < 8; ++ww) ss += red2[ww][slot][mr];
        norms[slot][mr] = 1.0f / fmaxf(sqrtf(ss), 1e-12f);
    }
    // combine 8 k-partials -> Sbuf (5 tiles x 256 entries)
    {
        const int tu[5] = {16, 16, 16, 0, 32};
        const int tv[5] = {0, 16, 32, 16, 16};
#pragma unroll
        for (int e = 0; e < 3; ++e) {
            int idx = tid + e * 512;
            if (idx < 1280) {
                int q = idx >> 8, r2 = idx & 255;
                int rho = r2 >> 4, kap = r2 & 15;
                float s4 = 0.f;
#pragma unroll
                for (int ww = 0; ww < 8; ++ww)
                    s4 += red[ww][q][rho * 17 + kap];
                Sbuf[tu[q] + rho][tv[q] + kap] = s4;
            }
        }
    }
    __syncthreads();

    // ---- epilogues (masks identical to validated rounds 7/9) ----
    float scale = expf(pscale[0]), bias = pbias[0];
    float loss = 0.0f;

    if (tid < 256) {
        // m2a by waves 0-3: query t = t0+i (row u = 16+i), cols v = tj*16+cc
        int i = tid >> 4, cc = tid & 15;
        float im_u = norms[1][i];
        float mmax = -1e30f, mpos = 0.0f;
#pragma unroll
        for (int tj = 0; tj < 3; ++tj) {
            int v  = tj * 16 + cc;
            int dd = v - i;                    // c - t + 16
            int c  = t0 - 16 + v;
            if (dd >= 0 && dd < 32 && c >= 0 && c < T_DIM) {
                float sv = Sbuf[16 + i][v] * norms[3 + tj][cc];  // s*inva[c]
                float logit = sv * im_u * scale + bias;
                bool pos = (dd >= 12) && (dd <= 19);
                loss += softplus(pos ? -logit : logit);
                if (sv > mmax) { mmax = sv; mpos = pos ? 1.0f : 0.0f; }
            }
        }
#pragma unroll
        for (int off = 1; off < 16; off <<= 1) {
            float ov = __shfl_xor(mmax, off, 64);
            float op = __shfl_xor(mpos, off, 64);
            if (ov > mmax) { mmax = ov; mpos = op; }
        }
        if (cc == 0) rowpos[i] = mpos;
    } else {
        // a2m by waves 4-7: query t = t0+i (col v = 16+i), rows u2 = tj*16+cc
        int t2 = tid - 256;
        int i = t2 >> 4, cc = t2 & 15;
        float ia_v = norms[4][i];
        float amax = -1e30f, apos = 0.0f;
#pragma unroll
        for (int tj = 0; tj < 3; ++tj) {
            int u2 = tj * 16 + cc;
            int ee = u2 - i;                   // r - t + 16
            int r  = t0 - 16 + u2;
            if (ee >= 0 && ee < 32 && r >= 0 && r < T_DIM) {
                float sv = Sbuf[u2][16 + i] * norms[tj][cc];     // s*invm[r]
                float logit = sv * ia_v * scale + bias;
                bool pos = (ee >= 12) && (ee <= 19);
                loss += softplus(pos ? -logit : logit);
                if (sv > amax) { amax = sv; apos = pos ? 1.0f : 0.0f; }
            }
        }
#pragma unroll
        for (int off = 1; off < 16; off <<= 1) {
            float ov = __shfl_xor(amax, off, 64);
            float op = __shfl_xor(apos, off, 64);
            if (ov > amax) { amax = ov; apos = op; }
        }
        if (cc == 0) colpos[i] = apos;
    }

    loss = wave_reduce_sum(loss);
    if (lane == 0) shl[w] = loss;
    __syncthreads();
    if (tid == 0) {
        float L = 0.0f, C = 0.0f;
#pragma unroll
        for (int r = 0; r < 8; ++r) L += shl[r];
#pragma unroll
        for (int r = 0; r < 16; ++r) C += rowpos[r] + colpos[r];
        part_loss[blk] = L;
        part_corr[blk] = C;
    }
}

__global__ __launch_bounds__(256) void finalsum_kernel(
    const float* __restrict__ part_loss, const float* __restrict__ part_corr,
    float* __restrict__ out)
{
    int tid = threadIdx.x;
    float l = part_loss[tid] + part_loss[tid + 256];
    float c = part_corr[tid] + part_corr[tid + 256];
    l = wave_reduce_sum(l);
    c = wave_reduce_sum(c);
    __shared__ float shl[4], shc[4];
    int w = tid >> 6, lane = tid & 63;
    if (lane == 0) { shl[w] = l; shc[w] = c; }
    __syncthreads();
    if (tid == 0) {
        out[0] = (shl[0] + shl[1] + shl[2] + shl[3]) / 16384.0f;
        out[1] = (shc[0] + shc[1] + shc[2] + shc[3]) / 16384.0f;
    }
}

extern "C" void kernel_launch(void* const* d_in, const int* in_sizes, int n_in,
                              void* d_out, int out_size, void* d_ws, size_t ws_size,
                              hipStream_t stream)
{
    const float* m  = (const float*)d_in[0];
    const float* a  = (const float*)d_in[1];
    const float* ps = (const float*)d_in[2];
    const float* pb = (const float*)d_in[3];
    float* out = (float*)d_out;

    float* part_loss = (float*)d_ws;          // 512
    float* part_corr = part_loss + NBLK;      // 512

    crossband_kernel<<<NBLK, 512, 0, stream>>>(m, a, ps, pb,
                                               part_loss, part_corr);
    finalsum_kernel<<<1, 256, 0, stream>>>(part_loss, part_corr, out);
}